// Round 2
// baseline (673.874 us; speedup 1.0000x reference)
//
#include <hip/hip_runtime.h>
#include <math.h>

// ---------------- CSR build ----------------
__global__ __launch_bounds__(256) void k_hist(const int* __restrict__ dst, int* __restrict__ deg, int E){
  int e = blockIdx.x*256 + threadIdx.x;
  if (e < E) atomicAdd(&deg[dst[e]], 1);
}

__global__ __launch_bounds__(256) void k_scan_local(const int* __restrict__ deg, int* __restrict__ offs,
    int* __restrict__ blksum, int nelem, int ndeg){
  __shared__ int sh[256];
  int t = threadIdx.x;
  int i = blockIdx.x*256 + t;
  int v = (i < ndeg) ? deg[i] : 0;
  sh[t] = v; __syncthreads();
  for (int d = 1; d < 256; d <<= 1){
    int add = (t >= d) ? sh[t-d] : 0; __syncthreads();
    sh[t] += add; __syncthreads();
  }
  if (i < nelem) offs[i] = sh[t] - v;   // exclusive
  if (t == 255) blksum[blockIdx.x] = sh[t];
}

__global__ __launch_bounds__(256) void k_scan_blk(int* __restrict__ blksum, int nb){
  __shared__ int sh[256];
  int t = threadIdx.x;
  int running = 0;
  for (int base = 0; base < nb; base += 256){
    int v = (base+t < nb) ? blksum[base+t] : 0;
    __syncthreads();
    sh[t] = v; __syncthreads();
    for (int d = 1; d < 256; d <<= 1){
      int add = (t >= d) ? sh[t-d] : 0; __syncthreads();
      sh[t] += add; __syncthreads();
    }
    if (base+t < nb) blksum[base+t] = running + sh[t] - v;
    running += sh[255];
  }
}

__global__ __launch_bounds__(256) void k_scan_add(int* __restrict__ offs, const int* __restrict__ blksum, int nelem){
  int i = blockIdx.x*256 + threadIdx.x;
  if (i < nelem) offs[i] += blksum[blockIdx.x];
}

__global__ __launch_bounds__(256) void k_scatter(const int* __restrict__ src, const int* __restrict__ dst,
    const int* __restrict__ offs, int* __restrict__ cursor, int* __restrict__ srcs, int E){
  int e = blockIdx.x*256 + threadIdx.x;
  if (e < E){
    int d = dst[e];
    int pos = offs[d] + atomicAdd(&cursor[d], 1);
    srcs[pos] = src[e];
  }
}

// ---------------- per-layer weight folding ----------------
// watt[j][k] (j<4: src head j, j>=4: dst head j-4) = sum_c W[k, h*64+c]*att[h,c]
// wbig[h*64+kk][c] = 0.25 * W[kk, h*64+c]   (head-mean folded in)
__global__ __launch_bounds__(512) void k_prep(const float* __restrict__ W, const float* __restrict__ att_src,
    const float* __restrict__ att_dst, float* __restrict__ watt, float* __restrict__ wbig){
  int t = threadIdx.x;
  int j = t >> 6, k = t & 63, h = j & 3;
  const float* att = (j < 4) ? att_src : att_dst;
  float s = 0.f;
  for (int c = 0; c < 64; ++c) s += W[k*256 + h*64 + c] * att[h*64 + c];
  watt[j*64 + k] = s;
  for (int i = t; i < 16384; i += 512){
    int hk = i >> 6, c = i & 63;
    int hh = hk >> 6, kk = hk & 63;
    wbig[i] = 0.25f * W[kk*256 + hh*64 + c];
  }
}

// ---------------- attention scalars: a_src/a_dst [N,4] ----------------
__global__ __launch_bounds__(256) void k_att(const float* __restrict__ feat, const float* __restrict__ watt,
    float* __restrict__ asrc, float* __restrict__ adst, int n){
  int tid = blockIdx.x*256 + threadIdx.x;
  if (tid >= n*8) return;
  int v = tid >> 3, j = tid & 7;
  const float4* f = (const float4*)(feat + (size_t)v*64);
  const float4* w = (const float4*)(watt + j*64);
  float s = 0.f;
  #pragma unroll
  for (int k = 0; k < 16; ++k){
    float4 a = f[k], b = w[k];
    s += a.x*b.x + a.y*b.y + a.z*b.z + a.w*b.w;
  }
  if (j < 4) asrc[v*4 + j] = s; else adst[v*4 + (j-4)] = s;
}

// ---------------- edge aggregation: one wave per dst node, online softmax ----------------
// 2-deep software pipeline: next edge's sid/asrc/feat issued before current edge's math.
__global__ __launch_bounds__(256) void k_agg(const float* __restrict__ feat, const float* __restrict__ asrc,
    const float* __restrict__ adst, const int* __restrict__ offs, const int* __restrict__ srcs,
    float* __restrict__ accx, int n){
  int wid = threadIdx.x >> 6;
  int lane = threadIdx.x & 63;
  int v = blockIdx.x*4 + wid;
  if (v >= n) return;
  int rs = offs[v], re = offs[v+1];
  float4 ad = *(const float4*)(adst + (size_t)v*4);
  float m0=-INFINITY, m1=-INFINITY, m2=-INFINITY, m3=-INFINITY;
  float s0=0.f, s1=0.f, s2=0.f, s3=0.f;
  float a0=0.f, a1=0.f, a2=0.f, a3=0.f;
  if (rs < re){
    int sid0 = srcs[rs];
    int sid1 = (rs+1 < re) ? srcs[rs+1] : sid0;
    float4 as0 = *(const float4*)(asrc + (size_t)sid0*4);
    float xk0 = feat[(size_t)sid0*64 + lane];
    for (int i = rs; i < re; ++i){
      float4 as1 = as0; float xk1 = xk0; int sid2 = sid1;
      if (i+1 < re){
        as1 = *(const float4*)(asrc + (size_t)sid1*4);   // issue early
        xk1 = feat[(size_t)sid1*64 + lane];              // issue early
        if (i+2 < re) sid2 = srcs[i+2];
      }
      {
        float l = as0.x + ad.x; l = fmaxf(l, 0.2f*l);
        float mn = fmaxf(m0, l);
        float sc = __expf(m0 - mn), p = __expf(l - mn);
        s0 = s0*sc + p; a0 = a0*sc + p*xk0; m0 = mn;
      }
      {
        float l = as0.y + ad.y; l = fmaxf(l, 0.2f*l);
        float mn = fmaxf(m1, l);
        float sc = __expf(m1 - mn), p = __expf(l - mn);
        s1 = s1*sc + p; a1 = a1*sc + p*xk0; m1 = mn;
      }
      {
        float l = as0.z + ad.z; l = fmaxf(l, 0.2f*l);
        float mn = fmaxf(m2, l);
        float sc = __expf(m2 - mn), p = __expf(l - mn);
        s2 = s2*sc + p; a2 = a2*sc + p*xk0; m2 = mn;
      }
      {
        float l = as0.w + ad.w; l = fmaxf(l, 0.2f*l);
        float mn = fmaxf(m3, l);
        float sc = __expf(m3 - mn), p = __expf(l - mn);
        s3 = s3*sc + p; a3 = a3*sc + p*xk0; m3 = mn;
      }
      as0 = as1; xk0 = xk1; sid1 = sid2;
    }
  }
  size_t base = (size_t)v*256 + lane;
  accx[base +   0] = a0 / (s0 + 1e-16f);   // deg==0 -> 0/eps = 0, matches segment_sum
  accx[base +  64] = a1 / (s1 + 1e-16f);
  accx[base + 128] = a2 / (s2 + 1e-16f);
  accx[base + 192] = a3 / (s3 + 1e-16f);
}

// ---------------- epilogue: out = accx @ wbig + feat @ lW + (bias+lb) (+relu) ----------------
// No LDS: W rows read as coalesced 256B dword loads from L2 (wbig/lW are L2-resident).
// Linear skip path fused in (k_lin eliminated).
__global__ __launch_bounds__(256) void k_out(const float* __restrict__ accx, const float* __restrict__ feat,
    const float* __restrict__ wbig, const float* __restrict__ lW,
    const float* __restrict__ bias, const float* __restrict__ lb,
    float* __restrict__ outp, int n, int do_relu){
  int lane = threadIdx.x & 63;
  int wid = threadIdx.x >> 6;
  int vb = blockIdx.x*32 + wid*8;
  const float* ap[8];
  const float* fp[8];
  #pragma unroll
  for (int j = 0; j < 8; ++j){
    int vj = vb + j; if (vj > n-1) vj = n-1;   // clamp: no OOB, tail masked at store
    ap[j] = accx + (size_t)vj*256;
    fp[j] = feat + (size_t)vj*64;
  }
  float acc[8] = {0,0,0,0,0,0,0,0};
  #pragma unroll 2
  for (int q4 = 0; q4 < 64; ++q4){
    float w0 = wbig[(q4*4+0)*64 + lane];   // coalesced 256B row reads
    float w1 = wbig[(q4*4+1)*64 + lane];
    float w2 = wbig[(q4*4+2)*64 + lane];
    float w3 = wbig[(q4*4+3)*64 + lane];
    #pragma unroll
    for (int j = 0; j < 8; ++j){
      float4 a = *(const float4*)(ap[j] + q4*4);   // wave-uniform 16B broadcast load
      acc[j] = fmaf(a.x, w0, acc[j]);
      acc[j] = fmaf(a.y, w1, acc[j]);
      acc[j] = fmaf(a.z, w2, acc[j]);
      acc[j] = fmaf(a.w, w3, acc[j]);
    }
  }
  // fused linear skip: feat @ lW
  #pragma unroll 2
  for (int k4 = 0; k4 < 16; ++k4){
    float w0 = lW[(k4*4+0)*64 + lane];
    float w1 = lW[(k4*4+1)*64 + lane];
    float w2 = lW[(k4*4+2)*64 + lane];
    float w3 = lW[(k4*4+3)*64 + lane];
    #pragma unroll
    for (int j = 0; j < 8; ++j){
      float4 f = *(const float4*)(fp[j] + k4*4);
      acc[j] = fmaf(f.x, w0, acc[j]);
      acc[j] = fmaf(f.y, w1, acc[j]);
      acc[j] = fmaf(f.z, w2, acc[j]);
      acc[j] = fmaf(f.w, w3, acc[j]);
    }
  }
  float bb = bias[lane] + lb[lane];
  #pragma unroll
  for (int j = 0; j < 8; ++j){
    int v = vb + j;
    if (v < n){
      float o = acc[j] + bb;
      if (do_relu) o = fmaxf(o, 0.f);
      outp[(size_t)v*64 + lane] = o;
    }
  }
}

extern "C" void kernel_launch(void* const* d_in, const int* in_sizes, int n_in,
                              void* d_out, int out_size, void* d_ws, size_t ws_size,
                              hipStream_t stream){
  const float* x   = (const float*)d_in[0];
  const int*   ei  = (const int*)d_in[1];
  const float* W1  = (const float*)d_in[2];
  const float* as1 = (const float*)d_in[3];
  const float* ad1 = (const float*)d_in[4];
  const float* b1  = (const float*)d_in[5];
  const float* lW1 = (const float*)d_in[6];
  const float* lb1 = (const float*)d_in[7];
  const float* W2  = (const float*)d_in[8];
  const float* as2 = (const float*)d_in[9];
  const float* ad2 = (const float*)d_in[10];
  const float* b2  = (const float*)d_in[11];
  const float* lW2 = (const float*)d_in[12];
  const float* lb2 = (const float*)d_in[13];
  int N = in_sizes[0] / 64;
  int E = in_sizes[1] / 2;
  const int* srce = ei;
  const int* dste = ei + E;

  char* w = (char*)d_ws;
  size_t off = 0;
  auto alloc = [&](size_t bytes)->char*{
    char* p = w + off; off = (off + bytes + 255) & ~(size_t)255; return p;
  };
  int*   offs   = (int*)  alloc((size_t)(N+1)*4);
  int*   deg    = (int*)  alloc((size_t)N*4);
  int*   cursor = (int*)  alloc((size_t)N*4);
  int*   blksum = (int*)  alloc(4096);
  int*   srcs   = (int*)  alloc((size_t)E*4);
  float* watt   = (float*)alloc(512*4);
  float* wbig   = (float*)alloc(16384*4);
  float* pasrc  = (float*)alloc((size_t)N*16);
  float* padst  = (float*)alloc((size_t)N*16);
  float* hbuf   = (float*)alloc((size_t)N*256);
  float* accx   = (float*)alloc((size_t)N*1024);
  (void)ws_size; (void)n_in; (void)out_size;

  // CSR by destination (built once, reused by both layers)
  hipMemsetAsync(deg, 0, (size_t)N*4, stream);
  hipMemsetAsync(cursor, 0, (size_t)N*4, stream);
  int gE = (E + 255)/256;
  k_hist<<<gE, 256, 0, stream>>>(dste, deg, E);
  int nelem = N + 1;
  int nb = (nelem + 255)/256;
  k_scan_local<<<nb, 256, 0, stream>>>(deg, offs, blksum, nelem, N);
  k_scan_blk<<<1, 256, 0, stream>>>(blksum, nb);
  k_scan_add<<<nb, 256, 0, stream>>>(offs, blksum, nelem);
  k_scatter<<<gE, 256, 0, stream>>>(srce, dste, offs, cursor, srcs, E);

  int gATT  = (N*8 + 255)/256;
  int ntile = (N + 31)/32;
  int gAGG  = (N + 3)/4;
  float* outp = (float*)d_out;

  // ----- layer 1 -----
  k_prep<<<1, 512, 0, stream>>>(W1, as1, ad1, watt, wbig);
  k_att <<<gATT, 256, 0, stream>>>(x, watt, pasrc, padst, N);
  k_agg <<<gAGG, 256, 0, stream>>>(x, pasrc, padst, offs, srcs, accx, N);
  k_out <<<ntile, 256, 0, stream>>>(accx, x, wbig, lW1, b1, lb1, hbuf, N, 1);

  // ----- layer 2 -----
  k_prep<<<1, 512, 0, stream>>>(W2, as2, ad2, watt, wbig);
  k_att <<<gATT, 256, 0, stream>>>(hbuf, watt, pasrc, padst, N);
  k_agg <<<gAGG, 256, 0, stream>>>(hbuf, pasrc, padst, offs, srcs, accx, N);
  k_out <<<ntile, 256, 0, stream>>>(accx, hbuf, wbig, lW2, b2, lb2, outp, N, 0);
}

// Round 3
// 358.233 us; speedup vs baseline: 1.8811x; 1.8811x over previous
//
#include <hip/hip_runtime.h>
#include <math.h>

typedef __attribute__((ext_vector_type(8))) short short8;
typedef __attribute__((ext_vector_type(4))) float f32x4;

__device__ inline unsigned fenc(float f){
  unsigned u = __float_as_uint(f);
  return u ^ ((u >> 31) ? 0xFFFFFFFFu : 0x80000000u);
}
__device__ inline float fdec(unsigned k){
  unsigned u = (k & 0x80000000u) ? (k ^ 0x80000000u) : ~k;
  return __uint_as_float(u);
}
__device__ inline short bf16rne(float f){
  unsigned u = __float_as_uint(f);
  return (short)((u + 0x7FFFu + ((u >> 16) & 1u)) >> 16);
}

// ---------------- CSR build ----------------
__global__ __launch_bounds__(256) void k_hist(const int* __restrict__ dst, int* __restrict__ deg, int E){
  int e = blockIdx.x*256 + threadIdx.x;
  if (e < E) atomicAdd(&deg[dst[e]], 1);
}

__global__ __launch_bounds__(256) void k_scan_local(const int* __restrict__ deg, int* __restrict__ offs,
    int* __restrict__ blksum, int nelem, int ndeg){
  __shared__ int sh[256];
  int t = threadIdx.x;
  int i = blockIdx.x*256 + t;
  int v = (i < ndeg) ? deg[i] : 0;
  sh[t] = v; __syncthreads();
  for (int d = 1; d < 256; d <<= 1){
    int add = (t >= d) ? sh[t-d] : 0; __syncthreads();
    sh[t] += add; __syncthreads();
  }
  if (i < nelem) offs[i] = sh[t] - v;   // exclusive
  if (t == 255) blksum[blockIdx.x] = sh[t];
}

__global__ __launch_bounds__(256) void k_scan_blk(int* __restrict__ blksum, int nb){
  __shared__ int sh[256];
  int t = threadIdx.x;
  int running = 0;
  for (int base = 0; base < nb; base += 256){
    int v = (base+t < nb) ? blksum[base+t] : 0;
    __syncthreads();
    sh[t] = v; __syncthreads();
    for (int d = 1; d < 256; d <<= 1){
      int add = (t >= d) ? sh[t-d] : 0; __syncthreads();
      sh[t] += add; __syncthreads();
    }
    if (base+t < nb) blksum[base+t] = running + sh[t] - v;
    running += sh[255];
  }
}

__global__ __launch_bounds__(256) void k_scan_add(int* __restrict__ offs, const int* __restrict__ blksum, int nelem){
  int i = blockIdx.x*256 + threadIdx.x;
  if (i < nelem) offs[i] += blksum[blockIdx.x];
}

__global__ __launch_bounds__(256) void k_scatter(const int* __restrict__ src, const int* __restrict__ dst,
    const int* __restrict__ offs, int* __restrict__ cursor, int* __restrict__ srcs, int E){
  int e = blockIdx.x*256 + threadIdx.x;
  if (e < E){
    int d = dst[e];
    int pos = offs[d] + atomicAdd(&cursor[d], 1);
    srcs[pos] = src[e];
  }
}

// ---------------- per-layer weight folding ----------------
// watt[j][k] = sum_c W[k, h*64+c]*att[h,c]  (j<4: src head j; j>=4: dst head j-4)
// wbigT (bf16, [64 cols][328 padded K]):
//   q<256:  B^T[c][q=h*64+cin] = 0.25*W[cin,h*64+c]   (head-mean folded)
//   256<=q<320: B^T[c][q] = lW[q-256, c]              (linear skip as extra K)
// bcomb[c] = b[c] + lb[c]
__global__ __launch_bounds__(512) void k_prep(const float* __restrict__ W, const float* __restrict__ att_src,
    const float* __restrict__ att_dst, const float* __restrict__ b, const float* __restrict__ lb,
    const float* __restrict__ lW,
    float* __restrict__ watt, short* __restrict__ wbigT, float* __restrict__ bcomb){
  int t = threadIdx.x;
  int j = t >> 6, k = t & 63, h = j & 3;
  const float* att = (j < 4) ? att_src : att_dst;
  float s = 0.f;
  for (int c = 0; c < 64; ++c) s += W[k*256 + h*64 + c] * att[h*64 + c];
  watt[j*64 + k] = s;
  if (t < 64) bcomb[t] = b[t] + lb[t];
  for (int i = t; i < 64*328; i += 512){
    int c = i / 328, q = i - c*328;
    float val = 0.f;
    if (q < 256){ int hh = q >> 6, cin = q & 63; val = 0.25f * W[cin*256 + hh*64 + c]; }
    else if (q < 320){ int kk = q - 256; val = lW[kk*64 + c]; }
    wbigT[i] = bf16rne(val);
  }
}

// ---------------- attention scalars + feat->bf16 copy + global a_src max ----------------
__global__ __launch_bounds__(256) void k_att(const float* __restrict__ feat, const float* __restrict__ watt,
    float* __restrict__ asrc, float* __restrict__ adst, short* __restrict__ Abf,
    unsigned* __restrict__ gmax, int n){
  __shared__ float sh[256];
  int t = threadIdx.x;
  int tid = blockIdx.x*256 + t;
  int v = tid >> 3, j = t & 7;
  int vc = (v < n) ? v : n-1;
  const float4* f = (const float4*)(feat + (size_t)vc*64);
  const float4* w = (const float4*)(watt + j*64);
  float s = 0.f;
  #pragma unroll
  for (int k = 0; k < 16; ++k){
    float4 a = f[k], b = w[k];
    s += a.x*b.x + a.y*b.y + a.z*b.z + a.w*b.w;
  }
  if (v < n){
    float4 c0 = f[j*2], c1 = f[j*2+1];
    short8 o;
    o[0]=bf16rne(c0.x); o[1]=bf16rne(c0.y); o[2]=bf16rne(c0.z); o[3]=bf16rne(c0.w);
    o[4]=bf16rne(c1.x); o[5]=bf16rne(c1.y); o[6]=bf16rne(c1.z); o[7]=bf16rne(c1.w);
    *(short8*)(Abf + (size_t)v*320 + 256 + j*8) = o;
    if (j < 4) asrc[v*4 + j] = s; else adst[v*4 + (j-4)] = s;
  }
  sh[t] = (v < n && j < 4) ? s : -INFINITY;
  __syncthreads();
  #pragma unroll
  for (int off = 128; off >= 8; off >>= 1){
    if (t < off) sh[t] = fmaxf(sh[t], sh[t+off]);
    __syncthreads();
  }
  if (t < 4) atomicMax(gmax + t, fenc(sh[t]));   // per-head global max of a_src
}

// ---------------- edge aggregation: one wave per dst node, fixed-reference softmax ----
// m_h(v) = leaky(gmax_h + a_dst[v,h]) >= every logit of v  (leaky monotone) -> p<=1.
// No online max: 1 exp + 2 fma per head per edge, no serial max dependency.
__global__ __launch_bounds__(256) void k_agg(const float* __restrict__ feat, const float* __restrict__ asrc,
    const float* __restrict__ adst, const int* __restrict__ offs, const int* __restrict__ srcs,
    const unsigned* __restrict__ gmax, short* __restrict__ Abf, int n){
  int wid = threadIdx.x >> 6;
  int lane = threadIdx.x & 63;
  int v = blockIdx.x*4 + wid;
  if (v >= n) return;
  int rs = offs[v], re = offs[v+1];
  float4 ad = *(const float4*)(adst + (size_t)v*4);
  float g0 = fdec(gmax[0]) + ad.x; g0 = fmaxf(g0, 0.2f*g0);
  float g1 = fdec(gmax[1]) + ad.y; g1 = fmaxf(g1, 0.2f*g1);
  float g2 = fdec(gmax[2]) + ad.z; g2 = fmaxf(g2, 0.2f*g2);
  float g3 = fdec(gmax[3]) + ad.w; g3 = fmaxf(g3, 0.2f*g3);
  float s0=0.f, s1=0.f, s2=0.f, s3=0.f;
  float a0=0.f, a1=0.f, a2=0.f, a3=0.f;
  if (rs < re){
    int sid0 = srcs[rs];
    int sid1 = (rs+1 < re) ? srcs[rs+1] : sid0;
    float4 as0 = *(const float4*)(asrc + (size_t)sid0*4);
    float xk0 = feat[(size_t)sid0*64 + lane];
    for (int i = rs; i < re; ++i){
      float4 as1 = as0; float xk1 = xk0; int sid2 = sid1;
      if (i+1 < re){
        as1 = *(const float4*)(asrc + (size_t)sid1*4);   // issue early
        xk1 = feat[(size_t)sid1*64 + lane];              // issue early
        if (i+2 < re) sid2 = srcs[i+2];
      }
      float l0 = as0.x + ad.x; l0 = fmaxf(l0, 0.2f*l0);
      float l1 = as0.y + ad.y; l1 = fmaxf(l1, 0.2f*l1);
      float l2 = as0.z + ad.z; l2 = fmaxf(l2, 0.2f*l2);
      float l3 = as0.w + ad.w; l3 = fmaxf(l3, 0.2f*l3);
      float p0 = __expf(l0 - g0);
      float p1 = __expf(l1 - g1);
      float p2 = __expf(l2 - g2);
      float p3 = __expf(l3 - g3);
      s0 += p0; a0 = fmaf(p0, xk0, a0);
      s1 += p1; a1 = fmaf(p1, xk0, a1);
      s2 += p2; a2 = fmaf(p2, xk0, a2);
      s3 += p3; a3 = fmaf(p3, xk0, a3);
      as0 = as1; xk0 = xk1; sid1 = sid2;
    }
  }
  size_t base = (size_t)v*320 + lane;
  Abf[base +   0] = bf16rne(a0 / (s0 + 1e-16f));   // deg==0 -> 0, matches reference
  Abf[base +  64] = bf16rne(a1 / (s1 + 1e-16f));
  Abf[base + 128] = bf16rne(a2 / (s2 + 1e-16f));
  Abf[base + 192] = bf16rne(a3 / (s3 + 1e-16f));
}

// ---------------- MFMA epilogue: out = A[N,320](bf16) @ B[320,64](bf16) + bcomb (+relu) ----
// Block: 4 waves x 16 rows = 64 rows. B staged in LDS as [64 cols][328] bf16 (pad -> 2-way max).
__global__ __launch_bounds__(256) void k_out(const short* __restrict__ Abf, const short* __restrict__ wbigT,
    const float* __restrict__ bcomb, float* __restrict__ outp, int n, int do_relu){
  __shared__ __align__(16) short sB[64*328];
  {
    const short8* gs = (const short8*)wbigT;
    short8* ls = (short8*)sB;
    for (int i = threadIdx.x; i < 64*328/8; i += 256) ls[i] = gs[i];
  }
  __syncthreads();
  int lane = threadIdx.x & 63, wid = threadIdx.x >> 6;
  int rowbase = blockIdx.x*64 + wid*16;
  int arow = rowbase + (lane & 15); if (arow > n-1) arow = n-1;
  int ksub = (lane >> 4) * 8;
  const short* ap = Abf + (size_t)arow*320 + ksub;
  const short* bp = sB + (lane & 15)*328 + ksub;
  f32x4 acc0 = {0.f,0.f,0.f,0.f}, acc1 = acc0, acc2 = acc0, acc3 = acc0;
  #pragma unroll
  for (int k0 = 0; k0 < 320; k0 += 32){
    short8 a  = *(const short8*)(ap + k0);
    short8 b0 = *(const short8*)(bp + k0);
    short8 b1 = *(const short8*)(bp + 16*328 + k0);
    short8 b2 = *(const short8*)(bp + 32*328 + k0);
    short8 b3 = *(const short8*)(bp + 48*328 + k0);
    acc0 = __builtin_amdgcn_mfma_f32_16x16x32_bf16(a, b0, acc0, 0, 0, 0);
    acc1 = __builtin_amdgcn_mfma_f32_16x16x32_bf16(a, b1, acc1, 0, 0, 0);
    acc2 = __builtin_amdgcn_mfma_f32_16x16x32_bf16(a, b2, acc2, 0, 0, 0);
    acc3 = __builtin_amdgcn_mfma_f32_16x16x32_bf16(a, b3, acc3, 0, 0, 0);
  }
  // C layout: col = lane&15, row = (lane>>4)*4 + r   [m89-verified]
  int ccol = lane & 15;
  int crow = rowbase + (lane >> 4)*4;
  float bb0 = bcomb[ 0 + ccol];
  float bb1 = bcomb[16 + ccol];
  float bb2 = bcomb[32 + ccol];
  float bb3 = bcomb[48 + ccol];
  #pragma unroll
  for (int r = 0; r < 4; ++r){
    int rr = crow + r;
    if (rr < n){
      float o0 = acc0[r] + bb0, o1 = acc1[r] + bb1, o2 = acc2[r] + bb2, o3 = acc3[r] + bb3;
      if (do_relu){ o0 = fmaxf(o0,0.f); o1 = fmaxf(o1,0.f); o2 = fmaxf(o2,0.f); o3 = fmaxf(o3,0.f); }
      float* orow = outp + (size_t)rr*64;
      orow[ 0 + ccol] = o0;
      orow[16 + ccol] = o1;
      orow[32 + ccol] = o2;
      orow[48 + ccol] = o3;
    }
  }
}

extern "C" void kernel_launch(void* const* d_in, const int* in_sizes, int n_in,
                              void* d_out, int out_size, void* d_ws, size_t ws_size,
                              hipStream_t stream){
  const float* x   = (const float*)d_in[0];
  const int*   ei  = (const int*)d_in[1];
  const float* W1  = (const float*)d_in[2];
  const float* as1 = (const float*)d_in[3];
  const float* ad1 = (const float*)d_in[4];
  const float* b1  = (const float*)d_in[5];
  const float* lW1 = (const float*)d_in[6];
  const float* lb1 = (const float*)d_in[7];
  const float* W2  = (const float*)d_in[8];
  const float* as2 = (const float*)d_in[9];
  const float* ad2 = (const float*)d_in[10];
  const float* b2  = (const float*)d_in[11];
  const float* lW2 = (const float*)d_in[12];
  const float* lb2 = (const float*)d_in[13];
  int N = in_sizes[0] / 64;
  int E = in_sizes[1] / 2;
  const int* srce = ei;
  const int* dste = ei + E;

  char* w = (char*)d_ws;
  size_t off = 0;
  auto alloc = [&](size_t bytes)->char*{
    char* p = w + off; off = (off + bytes + 255) & ~(size_t)255; return p;
  };
  int*      offs   = (int*)     alloc((size_t)(N+1)*4);
  int*      deg    = (int*)     alloc((size_t)N*4);
  int*      cursor = (int*)     alloc((size_t)N*4);
  int*      blksum = (int*)     alloc(4096);
  int*      srcs   = (int*)     alloc((size_t)E*4);
  float*    watt   = (float*)   alloc(512*4);
  short*    wbigT  = (short*)   alloc((size_t)64*328*2);
  float*    bcomb  = (float*)   alloc(64*4);
  unsigned* gmax   = (unsigned*)alloc(32);            // [0..3]=layer1, [4..7]=layer2
  float*    pasrc  = (float*)   alloc((size_t)N*16);
  float*    padst  = (float*)   alloc((size_t)N*16);
  float*    hbuf   = (float*)   alloc((size_t)N*256);
  short*    Abf    = (short*)   alloc((size_t)N*320*2);
  (void)ws_size; (void)n_in; (void)out_size;

  hipMemsetAsync(deg, 0, (size_t)N*4, stream);
  hipMemsetAsync(cursor, 0, (size_t)N*4, stream);
  hipMemsetAsync(gmax, 0, 32, stream);   // key 0 == uint minimum

  // CSR by destination (built once, reused by both layers)
  int gE = (E + 255)/256;
  k_hist<<<gE, 256, 0, stream>>>(dste, deg, E);
  int nelem = N + 1;
  int nb = (nelem + 255)/256;
  k_scan_local<<<nb, 256, 0, stream>>>(deg, offs, blksum, nelem, N);
  k_scan_blk<<<1, 256, 0, stream>>>(blksum, nb);
  k_scan_add<<<nb, 256, 0, stream>>>(offs, blksum, nelem);
  k_scatter<<<gE, 256, 0, stream>>>(srce, dste, offs, cursor, srcs, E);

  int gATT = (N*8 + 255)/256;
  int gAGG = (N + 3)/4;
  int gOUT = (N + 63)/64;
  float* outp = (float*)d_out;

  // ----- layer 1 -----
  k_prep<<<1, 512, 0, stream>>>(W1, as1, ad1, b1, lb1, lW1, watt, wbigT, bcomb);
  k_att <<<gATT, 256, 0, stream>>>(x, watt, pasrc, padst, Abf, gmax, N);
  k_agg <<<gAGG, 256, 0, stream>>>(x, pasrc, padst, offs, srcs, gmax, Abf, N);
  k_out <<<gOUT, 256, 0, stream>>>(Abf, wbigT, bcomb, hbuf, N, 1);

  // ----- layer 2 -----
  k_prep<<<1, 512, 0, stream>>>(W2, as2, ad2, b2, lb2, lW2, watt, wbigT, bcomb);
  k_att <<<gATT, 256, 0, stream>>>(hbuf, watt, pasrc, padst, Abf, gmax+4, N);
  k_agg <<<gAGG, 256, 0, stream>>>(hbuf, pasrc, padst, offs, srcs, gmax+4, Abf, N);
  k_out <<<gOUT, 256, 0, stream>>>(Abf, wbigT, bcomb, outp, N, 0);
}